// Round 11
// baseline (944.587 us; speedup 1.0000x reference)
//
#include <hip/hip_runtime.h>
#include <hip/hip_bf16.h>
#include <math.h>

#define N_NODES 16384
#define NB      32
#define S_PG    512
#define NE      262144
#define EPG     8192
#define D       256
#define D2      512
#define D3      768
#define NL      4
#define NH      4
#define DHD     64
#define OUTD    768
#define NCOMBO  264
#define WT_PER_LAYER 786432
#define INV_N   (1.0f / (float)N_NODES)
#define QSCALE  0.1803368801111244f   // 0.125 * log2(e)

typedef short s8v __attribute__((ext_vector_type(8)));
typedef float f4v __attribute__((ext_vector_type(4)));

__device__ __forceinline__ unsigned bfr(float f) {   // fp32 -> bf16 bits, RNE
    unsigned u = __float_as_uint(f);
    return (u + 0x7fffu + ((u >> 16) & 1u)) >> 16;
}
__device__ __forceinline__ float b2f(unsigned short u) {
    return __uint_as_float(((unsigned)u) << 16);
}

// ---------------- Atom encoder: h (f32) + hb (bf16) ----------------
__global__ __launch_bounds__(256) void k_atom_enc(const int* __restrict__ x,
                                                  const float* __restrict__ tab,
                                                  float* __restrict__ h,
                                                  unsigned short* __restrict__ hb) {
    int node = blockIdx.x * 4 + (threadIdx.x >> 6);
    int lane = threadIdx.x & 63;
    int dd = lane << 2;
    float4 acc = {0.f, 0.f, 0.f, 0.f};
#pragma unroll
    for (int f = 0; f < 9; ++f) {
        int v = x[node * 9 + f];
        const float4 t = *(const float4*)&tab[((size_t)(f * 119 + v)) * D + dd];
        acc.x += t.x; acc.y += t.y; acc.z += t.z; acc.w += t.w;
    }
    *(float4*)&h[(size_t)node * D + dd] = acc;
    ushort4 o;
    o.x = (unsigned short)bfr(acc.x); o.y = (unsigned short)bfr(acc.y);
    o.z = (unsigned short)bfr(acc.z); o.w = (unsigned short)bfr(acc.w);
    *(ushort4*)&hb[(size_t)node * D + dd] = o;
}

// ---------------- bw[l,fv,:] = bond_tab[fv,:] @ elin_w[l] ----------------
__global__ __launch_bounds__(256) void k_bondw(const float* __restrict__ bond_tab,
                                               const float* __restrict__ elin_w,
                                               float* __restrict__ bw) {
    int blk = blockIdx.x;         // L*66
    int l = blk / 66, fv = blk % 66;
    int dout = threadIdx.x;
    const float* tabrow = bond_tab + (size_t)fv * D;
    const float* w = elin_w + (size_t)l * D * D;
    float acc = 0.f;
    for (int d = 0; d < D; ++d) acc = fmaf(tabrow[d], w[d * D + dout], acc);
    bw[((size_t)l * 66 + fv) * D + dout] = acc;
}

// ---------------- combo table (bf16) ----------------
__global__ __launch_bounds__(256) void k_combo(const float* __restrict__ bw,
                                               const float* __restrict__ elin_b,
                                               unsigned short* __restrict__ ctb) {
    int b = blockIdx.x;           // NL*264
    int l = b / NCOMBO, cid = b % NCOMBO;
    int a0 = cid / 12, a1 = (cid % 12) / 2, a2 = cid & 1;
    int d = threadIdx.x;
    const float* bwl = bw + (size_t)l * 66 * D;
    float v = bwl[(size_t)a0 * D + d] + bwl[(size_t)(22 + a1) * D + d] +
              bwl[(size_t)(44 + a2) * D + d] + elin_b[(size_t)l * D + d];
    ctb[((size_t)l * NCOMBO + cid) * D + d] = (unsigned short)bfr(v);
}

// ---------------- CSR build ----------------
__global__ __launch_bounds__(256) void k_zero16k(int* __restrict__ p) {
    p[blockIdx.x * 256 + threadIdx.x] = 0;
}
__global__ __launch_bounds__(256) void k_zero_stats12(float* __restrict__ p) {
    for (int i = 0; i < 24; ++i) p[i * 256 + threadIdx.x] = 0.f;   // 12 slots x 512
}
__global__ __launch_bounds__(256) void k_hist(const int* __restrict__ dst, int* __restrict__ deg) {
    int e = blockIdx.x * 256 + threadIdx.x;
    atomicAdd(&deg[dst[e]], 1);
}
__global__ __launch_bounds__(256) void k_scan(const int* __restrict__ deg,
                                              int* __restrict__ row_ptr,
                                              int* __restrict__ cursor) {
    __shared__ int partial[256];
    int t = threadIdx.x;
    int base = t * 64;
    int s = 0;
    for (int i = 0; i < 64; ++i) s += deg[base + i];
    partial[t] = s;
    __syncthreads();
    for (int dstp = 1; dstp < 256; dstp <<= 1) {
        int v = (t >= dstp) ? partial[t - dstp] : 0;
        __syncthreads();
        partial[t] += v;
        __syncthreads();
    }
    int run = partial[t] - s;
    for (int i = 0; i < 64; ++i) {
        int dcur = deg[base + i];
        row_ptr[base + i] = run;
        cursor[base + i] = run;
        run += dcur;
    }
    if (t == 255) row_ptr[N_NODES] = run;
}
__global__ __launch_bounds__(256) void k_scatter(const int* __restrict__ src,
                                                 const int* __restrict__ dst,
                                                 const int* __restrict__ ea,
                                                 int* __restrict__ cursor,
                                                 int2* __restrict__ sorted) {
    int e = blockIdx.x * 256 + threadIdx.x;
    int d = dst[e];
    int pos = atomicAdd(&cursor[d], 1);
    int cid = ea[e * 3] * 12 + ea[e * 3 + 1] * 2 + ea[e * 3 + 2];
    sorted[pos] = make_int2(src[e], cid);
}

// ---------------- GINE aggregation (bf16 gather) ----------------
__global__ __launch_bounds__(256) void k_gine_agg(const unsigned short* __restrict__ hb,
                                                  const float* __restrict__ h,
                                                  const unsigned short* __restrict__ ctb,
                                                  const float* __restrict__ eps, int l,
                                                  const int* __restrict__ row_ptr,
                                                  const int2* __restrict__ sorted,
                                                  unsigned short* __restrict__ aggb) {
    int w = threadIdx.x >> 6;
    int lane = threadIdx.x & 63;
    int n = blockIdx.x * 4 + w;
    int dd = lane << 2;
    int beg = row_ptr[n], end = row_ptr[n + 1];
    float4 acc = {0.f, 0.f, 0.f, 0.f};
    int i = beg;
    for (; i + 2 <= end; i += 2) {
        int2 e0 = sorted[i];
        int2 e1 = sorted[i + 1];
        ushort4 h0 = *(const ushort4*)&hb[(size_t)e0.x * D + dd];
        ushort4 c0 = *(const ushort4*)&ctb[(size_t)e0.y * D + dd];
        ushort4 h1 = *(const ushort4*)&hb[(size_t)e1.x * D + dd];
        ushort4 c1 = *(const ushort4*)&ctb[(size_t)e1.y * D + dd];
        acc.x += fmaxf(b2f(h0.x) + b2f(c0.x), 0.f) + fmaxf(b2f(h1.x) + b2f(c1.x), 0.f);
        acc.y += fmaxf(b2f(h0.y) + b2f(c0.y), 0.f) + fmaxf(b2f(h1.y) + b2f(c1.y), 0.f);
        acc.z += fmaxf(b2f(h0.z) + b2f(c0.z), 0.f) + fmaxf(b2f(h1.z) + b2f(c1.z), 0.f);
        acc.w += fmaxf(b2f(h0.w) + b2f(c0.w), 0.f) + fmaxf(b2f(h1.w) + b2f(c1.w), 0.f);
    }
    if (i < end) {
        int2 e0 = sorted[i];
        ushort4 h0 = *(const ushort4*)&hb[(size_t)e0.x * D + dd];
        ushort4 c0 = *(const ushort4*)&ctb[(size_t)e0.y * D + dd];
        acc.x += fmaxf(b2f(h0.x) + b2f(c0.x), 0.f);
        acc.y += fmaxf(b2f(h0.y) + b2f(c0.y), 0.f);
        acc.z += fmaxf(b2f(h0.z) + b2f(c0.z), 0.f);
        acc.w += fmaxf(b2f(h0.w) + b2f(c0.w), 0.f);
    }
    float s1p = 1.f + eps[l];
    float4 hn = *(const float4*)&h[(size_t)n * D + dd];
    ushort4 o;
    o.x = (unsigned short)bfr(s1p * hn.x + acc.x);
    o.y = (unsigned short)bfr(s1p * hn.y + acc.y);
    o.z = (unsigned short)bfr(s1p * hn.z + acc.z);
    o.w = (unsigned short)bfr(s1p * hn.w + acc.w);
    *(ushort4*)&aggb[(size_t)n * D + dd] = o;
}

// ---------------- weight transpose+convert ----------------
__global__ __launch_bounds__(256) void k_wcvt(const float* __restrict__ gw1, const float* __restrict__ gw2,
                                              const float* __restrict__ aw_in, const float* __restrict__ aw_out,
                                              const float* __restrict__ mw1, const float* __restrict__ mw2,
                                              unsigned short* __restrict__ WT) {
    const int KS[6]   = {256, 512, 256, 256, 256, 512};
    const int NS[6]   = {512, 256, 768, 256, 512, 256};
    const int TOFF[7] = {0, 128, 256, 448, 512, 640, 768};
    const int DOFF[6] = {0, 131072, 262144, 458752, 524288, 655360};
    int b = blockIdx.x;
    int l = b / 768, wb = b % 768;
    int widx = 0;
    while (wb >= TOFF[widx + 1]) ++widx;
    int t = wb - TOFF[widx];
    int K = KS[widx], N = NS[widx];
    int nn = N / 32;
    int kt = t / nn, nt = t % nn;
    const float* srcs[6] = {gw1, gw2, aw_in, aw_out, mw1, mw2};
    const float* W = srcs[widx] + (size_t)l * K * N;
    unsigned short* WTp = WT + (size_t)l * WT_PER_LAYER + DOFF[widx];
    __shared__ float tile[32][33];
    int tid = threadIdx.x;
    int r = tid >> 3, c4 = (tid & 7) << 2;
    float4 v = *(const float4*)&W[(size_t)(kt * 32 + r) * N + nt * 32 + c4];
    tile[r][c4] = v.x; tile[r][c4 + 1] = v.y; tile[r][c4 + 2] = v.z; tile[r][c4 + 3] = v.w;
    __syncthreads();
    int nr = tid >> 3, kc = (tid & 7) << 2;
    ushort4 o;
    o.x = (unsigned short)bfr(tile[kc + 0][nr]);
    o.y = (unsigned short)bfr(tile[kc + 1][nr]);
    o.z = (unsigned short)bfr(tile[kc + 2][nr]);
    o.w = (unsigned short)bfr(tile[kc + 3][nr]);
    *(ushort4*)&WTp[(size_t)(nt * 32 + nr) * K + kt * 32 + kc] = o;
}

// ---------------- BM=128 bf16 MFMA GEMM (single) ----------------
template<int RELU, int RES, int OBF, int STAT>
__global__ __launch_bounds__(256) void k_mm2(const unsigned short* __restrict__ A,
                                             const unsigned short* __restrict__ BT,
                                             const float* __restrict__ bias,
                                             const float* __restrict__ res,
                                             void* __restrict__ Cp,
                                             float* __restrict__ stat,
                                             int M, int N, int K) {
    __shared__ unsigned short As[128 * 64];
    __shared__ unsigned short Bs[128 * 64];
    const int tid = threadIdx.x;
    const int row0 = blockIdx.y * 128, col0 = blockIdx.x * 128;
    const int w = tid >> 6, l = tid & 63;
    const int wm = w >> 1, wn = w & 1;
    const int lr = l & 15, lq = l >> 4;
    const int srow = l >> 3;
    const int scol = (l & 7) * 8;
    f4v acc[4][4] = {};

    const unsigned short* Ag = A + (size_t)(row0 + w * 32 + srow) * K + scol;
    const unsigned short* Bg = BT + (size_t)(col0 + w * 32 + srow) * K + scol;
    unsigned short* Al = &As[(w * 32) * 64];
    unsigned short* Bl = &Bs[(w * 32) * 64];

    for (int k0 = 0; k0 < K; k0 += 64) {
#pragma unroll
        for (int it = 0; it < 4; ++it) {
            __builtin_amdgcn_global_load_lds(
                (const __attribute__((address_space(1))) unsigned*)(Ag + (size_t)(it * 8) * K + k0),
                (__attribute__((address_space(3))) unsigned*)(Al + it * 8 * 64), 16, 0, 0);
            __builtin_amdgcn_global_load_lds(
                (const __attribute__((address_space(1))) unsigned*)(Bg + (size_t)(it * 8) * K + k0),
                (__attribute__((address_space(3))) unsigned*)(Bl + it * 8 * 64), 16, 0, 0);
        }
        asm volatile("s_waitcnt vmcnt(0)" ::: "memory");
        __syncthreads();
#pragma unroll
        for (int kk = 0; kk < 2; ++kk) {
            s8v af[4], bf[4];
#pragma unroll
            for (int m = 0; m < 4; ++m)
                af[m] = *(const s8v*)&As[(wm * 64 + m * 16 + lr) * 64 + kk * 32 + lq * 8];
#pragma unroll
            for (int n = 0; n < 4; ++n)
                bf[n] = *(const s8v*)&Bs[(wn * 64 + n * 16 + lr) * 64 + kk * 32 + lq * 8];
#pragma unroll
            for (int m = 0; m < 4; ++m)
#pragma unroll
                for (int n = 0; n < 4; ++n)
                    acc[m][n] = __builtin_amdgcn_mfma_f32_16x16x32_bf16(af[m], bf[n], acc[m][n], 0, 0, 0);
        }
        __syncthreads();
    }
    float cs[4], cs2[4];
#pragma unroll
    for (int n = 0; n < 4; ++n) { cs[n] = 0.f; cs2[n] = 0.f; }
#pragma unroll
    for (int n = 0; n < 4; ++n) {
        int c = col0 + wn * 64 + n * 16 + lr;
        float bv = bias[c];
#pragma unroll
        for (int m = 0; m < 4; ++m) {
#pragma unroll
            for (int j = 0; j < 4; ++j) {
                int r = row0 + wm * 64 + m * 16 + lq * 4 + j;
                float v = acc[m][n][j] + bv;
                if (RES) v += res[(size_t)r * N + c];
                if (STAT) { cs[n] += v; cs2[n] += v * v; }
                if (RELU) v = fmaxf(v, 0.f);
                if (OBF) ((unsigned short*)Cp)[(size_t)r * N + c] = (unsigned short)bfr(v);
                else ((float*)Cp)[(size_t)r * N + c] = v;
            }
        }
    }
    if (STAT) {
#pragma unroll
        for (int n = 0; n < 4; ++n) {
            float s = cs[n], s2 = cs2[n];
            s += __shfl_xor(s, 16);  s2 += __shfl_xor(s2, 16);
            s += __shfl_xor(s, 32);  s2 += __shfl_xor(s2, 32);
            if (lq == 0) {
                int c = col0 + wn * 64 + n * 16 + lr;
                atomicAdd(&stat[c], s);
                atomicAdd(&stat[256 + c], s2);
            }
        }
    }
}

// ---------------- dual GEMM dispatch (BM=128): gw1 (relu) + aw_in (Q prescaled) ----------------
__global__ __launch_bounds__(256) void k_mm2_dual(const unsigned short* __restrict__ A1,
                                                  const unsigned short* __restrict__ B1,
                                                  const float* __restrict__ bias1,
                                                  unsigned short* __restrict__ C1, int N1, int nb1,
                                                  const unsigned short* __restrict__ A2,
                                                  const unsigned short* __restrict__ B2,
                                                  const float* __restrict__ bias2,
                                                  unsigned short* __restrict__ C2, int N2,
                                                  int K) {
    __shared__ unsigned short As[128 * 64];
    __shared__ unsigned short Bs[128 * 64];
    const unsigned short* A; const unsigned short* BT; const float* bias;
    unsigned short* C; int N, cb, relu;
    if ((int)blockIdx.x < nb1) { A = A1; BT = B1; bias = bias1; C = C1; N = N1; cb = blockIdx.x; relu = 1; }
    else { A = A2; BT = B2; bias = bias2; C = C2; N = N2; cb = blockIdx.x - nb1; relu = 0; }
    const int tid = threadIdx.x;
    const int row0 = blockIdx.y * 128, col0 = cb * 128;
    const int w = tid >> 6, l = tid & 63;
    const int wm = w >> 1, wn = w & 1;
    const int lr = l & 15, lq = l >> 4;
    const int srow = l >> 3;
    const int scol = (l & 7) * 8;
    f4v acc[4][4] = {};

    const unsigned short* Ag = A + (size_t)(row0 + w * 32 + srow) * K + scol;
    const unsigned short* Bg = BT + (size_t)(col0 + w * 32 + srow) * K + scol;
    unsigned short* Al = &As[(w * 32) * 64];
    unsigned short* Bl = &Bs[(w * 32) * 64];

    for (int k0 = 0; k0 < K; k0 += 64) {
#pragma unroll
        for (int it = 0; it < 4; ++it) {
            __builtin_amdgcn_global_load_lds(
                (const __attribute__((address_space(1))) unsigned*)(Ag + (size_t)(it * 8) * K + k0),
                (__attribute__((address_space(3))) unsigned*)(Al + it * 8 * 64), 16, 0, 0);
            __builtin_amdgcn_global_load_lds(
                (const __attribute__((address_space(1))) unsigned*)(Bg + (size_t)(it * 8) * K + k0),
                (__attribute__((address_space(3))) unsigned*)(Bl + it * 8 * 64), 16, 0, 0);
        }
        asm volatile("s_waitcnt vmcnt(0)" ::: "memory");
        __syncthreads();
#pragma unroll
        for (int kk = 0; kk < 2; ++kk) {
            s8v af[4], bf[4];
#pragma unroll
            for (int m = 0; m < 4; ++m)
                af[m] = *(const s8v*)&As[(wm * 64 + m * 16 + lr) * 64 + kk * 32 + lq * 8];
#pragma unroll
            for (int n = 0; n < 4; ++n)
                bf[n] = *(const s8v*)&Bs[(wn * 64 + n * 16 + lr) * 64 + kk * 32 + lq * 8];
#pragma unroll
            for (int m = 0; m < 4; ++m)
#pragma unroll
                for (int n = 0; n < 4; ++n)
                    acc[m][n] = __builtin_amdgcn_mfma_f32_16x16x32_bf16(af[m], bf[n], acc[m][n], 0, 0, 0);
        }
        __syncthreads();
    }
#pragma unroll
    for (int n = 0; n < 4; ++n) {
        int c = col0 + wn * 64 + n * 16 + lr;
        float bv = bias[c];
#pragma unroll
        for (int m = 0; m < 4; ++m) {
#pragma unroll
            for (int j = 0; j < 4; ++j) {
                int r = row0 + wm * 64 + m * 16 + lq * 4 + j;
                float v = acc[m][n][j] + bv;
                if (relu) v = fmaxf(v, 0.f);
                else if (c < 256) v *= QSCALE;      // Q columns: fold 0.125*log2(e)
                C[(size_t)r * N + c] = (unsigned short)bfr(v);
            }
        }
    }
}

// ---------------- BM=64 bf16 MFMA GEMM (single, N=256 shapes) ----------------
template<int RELU, int RES, int OBF, int STAT>
__global__ __launch_bounds__(256) void k_mm64(const unsigned short* __restrict__ A,
                                              const unsigned short* __restrict__ BT,
                                              const float* __restrict__ bias,
                                              const float* __restrict__ res,
                                              void* __restrict__ Cp,
                                              float* __restrict__ stat,
                                              int M, int N, int K) {
    __shared__ unsigned short As[64 * 64];
    __shared__ unsigned short Bs[128 * 64];
    const int tid = threadIdx.x;
    const int row0 = blockIdx.y * 64, col0 = blockIdx.x * 128;
    const int w = tid >> 6, l = tid & 63;
    const int wn = w;
    const int lr = l & 15, lq = l >> 4;
    const int srow = l >> 3;
    const int scol = (l & 7) * 8;
    f4v acc[4][2] = {};

    const unsigned short* Ag = A + (size_t)(row0 + w * 16 + srow) * K + scol;
    const unsigned short* Bg = BT + (size_t)(col0 + w * 32 + srow) * K + scol;
    unsigned short* Al = &As[(w * 16) * 64];
    unsigned short* Bl = &Bs[(w * 32) * 64];

    for (int k0 = 0; k0 < K; k0 += 64) {
#pragma unroll
        for (int it = 0; it < 2; ++it)
            __builtin_amdgcn_global_load_lds(
                (const __attribute__((address_space(1))) unsigned*)(Ag + (size_t)(it * 8) * K + k0),
                (__attribute__((address_space(3))) unsigned*)(Al + it * 8 * 64), 16, 0, 0);
#pragma unroll
        for (int it = 0; it < 4; ++it)
            __builtin_amdgcn_global_load_lds(
                (const __attribute__((address_space(1))) unsigned*)(Bg + (size_t)(it * 8) * K + k0),
                (__attribute__((address_space(3))) unsigned*)(Bl + it * 8 * 64), 16, 0, 0);
        asm volatile("s_waitcnt vmcnt(0)" ::: "memory");
        __syncthreads();
#pragma unroll
        for (int kk = 0; kk < 2; ++kk) {
            s8v af[4], bf[2];
#pragma unroll
            for (int m = 0; m < 4; ++m)
                af[m] = *(const s8v*)&As[(m * 16 + lr) * 64 + kk * 32 + lq * 8];
#pragma unroll
            for (int n = 0; n < 2; ++n)
                bf[n] = *(const s8v*)&Bs[(wn * 32 + n * 16 + lr) * 64 + kk * 32 + lq * 8];
#pragma unroll
            for (int m = 0; m < 4; ++m)
#pragma unroll
                for (int n = 0; n < 2; ++n)
                    acc[m][n] = __builtin_amdgcn_mfma_f32_16x16x32_bf16(af[m], bf[n], acc[m][n], 0, 0, 0);
        }
        __syncthreads();
    }
    float cs[2], cs2[2];
#pragma unroll
    for (int n = 0; n < 2; ++n) { cs[n] = 0.f; cs2[n] = 0.f; }
#pragma unroll
    for (int n = 0; n < 2; ++n) {
        int c = col0 + wn * 32 + n * 16 + lr;
        float bv = bias[c];
#pragma unroll
        for (int m = 0; m < 4; ++m) {
#pragma unroll
            for (int j = 0; j < 4; ++j) {
                int r = row0 + m * 16 + lq * 4 + j;
                float v = acc[m][n][j] + bv;
                if (RES) v += res[(size_t)r * N + c];
                if (STAT) { cs[n] += v; cs2[n] += v * v; }
                if (RELU) v = fmaxf(v, 0.f);
                if (OBF) ((unsigned short*)Cp)[(size_t)r * N + c] = (unsigned short)bfr(v);
                else ((float*)Cp)[(size_t)r * N + c] = v;
            }
        }
    }
    if (STAT) {
#pragma unroll
        for (int n = 0; n < 2; ++n) {
            float s = cs[n], s2 = cs2[n];
            s += __shfl_xor(s, 16);  s2 += __shfl_xor(s2, 16);
            s += __shfl_xor(s, 32);  s2 += __shfl_xor(s2, 32);
            if (lq == 0) {
                int c = col0 + wn * 32 + n * 16 + lr;
                atomicAdd(&stat[c], s);
                atomicAdd(&stat[256 + c], s2);
            }
        }
    }
}

// ---------------- dual BM=64 GEMM: gw2 (K=512) + aw_out (K=256), both RES+STAT, f32 out ----------------
__global__ __launch_bounds__(256) void k_mm64_dual(const unsigned short* __restrict__ A1,
                                                   const unsigned short* __restrict__ B1,
                                                   const float* __restrict__ bias1,
                                                   const float* __restrict__ res1,
                                                   float* __restrict__ C1,
                                                   float* __restrict__ stat1, int K1, int nb1,
                                                   const unsigned short* __restrict__ A2,
                                                   const unsigned short* __restrict__ B2,
                                                   const float* __restrict__ bias2,
                                                   const float* __restrict__ res2,
                                                   float* __restrict__ C2,
                                                   float* __restrict__ stat2, int K2) {
    __shared__ unsigned short As[64 * 64];
    __shared__ unsigned short Bs[128 * 64];
    const unsigned short *A, *BT; const float *bias, *res; float *C, *stat;
    int K, cb;
    if ((int)blockIdx.x < nb1) { A = A1; BT = B1; bias = bias1; res = res1; C = C1; stat = stat1; K = K1; cb = blockIdx.x; }
    else { A = A2; BT = B2; bias = bias2; res = res2; C = C2; stat = stat2; K = K2; cb = blockIdx.x - nb1; }
    const int N = 256;
    const int tid = threadIdx.x;
    const int row0 = blockIdx.y * 64, col0 = cb * 128;
    const int w = tid >> 6, l = tid & 63;
    const int wn = w;
    const int lr = l & 15, lq = l >> 4;
    const int srow = l >> 3;
    const int scol = (l & 7) * 8;
    f4v acc[4][2] = {};

    const unsigned short* Ag = A + (size_t)(row0 + w * 16 + srow) * K + scol;
    const unsigned short* Bg = BT + (size_t)(col0 + w * 32 + srow) * K + scol;
    unsigned short* Al = &As[(w * 16) * 64];
    unsigned short* Bl = &Bs[(w * 32) * 64];

    for (int k0 = 0; k0 < K; k0 += 64) {
#pragma unroll
        for (int it = 0; it < 2; ++it)
            __builtin_amdgcn_global_load_lds(
                (const __attribute__((address_space(1))) unsigned*)(Ag + (size_t)(it * 8) * K + k0),
                (__attribute__((address_space(3))) unsigned*)(Al + it * 8 * 64), 16, 0, 0);
#pragma unroll
        for (int it = 0; it < 4; ++it)
            __builtin_amdgcn_global_load_lds(
                (const __attribute__((address_space(1))) unsigned*)(Bg + (size_t)(it * 8) * K + k0),
                (__attribute__((address_space(3))) unsigned*)(Bl + it * 8 * 64), 16, 0, 0);
        asm volatile("s_waitcnt vmcnt(0)" ::: "memory");
        __syncthreads();
#pragma unroll
        for (int kk = 0; kk < 2; ++kk) {
            s8v af[4], bf[2];
#pragma unroll
            for (int m = 0; m < 4; ++m)
                af[m] = *(const s8v*)&As[(m * 16 + lr) * 64 + kk * 32 + lq * 8];
#pragma unroll
            for (int n = 0; n < 2; ++n)
                bf[n] = *(const s8v*)&Bs[(wn * 32 + n * 16 + lr) * 64 + kk * 32 + lq * 8];
#pragma unroll
            for (int m = 0; m < 4; ++m)
#pragma unroll
                for (int n = 0; n < 2; ++n)
                    acc[m][n] = __builtin_amdgcn_mfma_f32_16x16x32_bf16(af[m], bf[n], acc[m][n], 0, 0, 0);
        }
        __syncthreads();
    }
    float cs[2], cs2[2];
#pragma unroll
    for (int n = 0; n < 2; ++n) { cs[n] = 0.f; cs2[n] = 0.f; }
#pragma unroll
    for (int n = 0; n < 2; ++n) {
        int c = col0 + wn * 32 + n * 16 + lr;
        float bv = bias[c];
#pragma unroll
        for (int m = 0; m < 4; ++m) {
#pragma unroll
            for (int j = 0; j < 4; ++j) {
                int r = row0 + m * 16 + lq * 4 + j;
                float v = acc[m][n][j] + bv + res[(size_t)r * N + c];
                cs[n] += v; cs2[n] += v * v;
                C[(size_t)r * N + c] = v;
            }
        }
    }
#pragma unroll
    for (int n = 0; n < 2; ++n) {
        float s = cs[n], s2 = cs2[n];
        s += __shfl_xor(s, 16);  s2 += __shfl_xor(s2, 16);
        s += __shfl_xor(s, 32);  s2 += __shfl_xor(s2, 32);
        if (lq == 0) {
            int c = col0 + wn * 32 + n * 16 + lr;
            atomicAdd(&stat[c], s);
            atomicAdd(&stat[256 + c], s2);
        }
    }
}

// ---------------- fused: y = bn1(t1) + bn2(t2), inline stats, dual write ----------------
__global__ __launch_bounds__(256) void k_bn12i(const float* __restrict__ t1,
                                               const float* __restrict__ sa1,
                                               const float* __restrict__ g1,
                                               const float* __restrict__ b1,
                                               const float* __restrict__ t2,
                                               const float* __restrict__ sa2,
                                               const float* __restrict__ g2,
                                               const float* __restrict__ b2,
                                               float* __restrict__ y,
                                               unsigned short* __restrict__ yb) {
    size_t i4 = (size_t)blockIdx.x * blockDim.x + threadIdx.x;
    int c = (int)((i4 & 63) << 2);
    float a1[4], a2[4], o[4];
    *(float4*)a1 = ((const float4*)t1)[i4];
    *(float4*)a2 = ((const float4*)t2)[i4];
#pragma unroll
    for (int q = 0; q < 4; ++q) {
        int cc = c + q;
        float m1 = sa1[cc] * INV_N;
        float r1 = rsqrtf(sa1[256 + cc] * INV_N - m1 * m1 + 1e-5f);
        float m2 = sa2[cc] * INV_N;
        float r2 = rsqrtf(sa2[256 + cc] * INV_N - m2 * m2 + 1e-5f);
        o[q] = (a1[q] - m1) * r1 * g1[cc] + b1[cc] + (a2[q] - m2) * r2 * g2[cc] + b2[cc];
    }
    ((float4*)y)[i4] = *(float4*)o;
    ushort4 ob;
    ob.x = (unsigned short)bfr(o[0]); ob.y = (unsigned short)bfr(o[1]);
    ob.z = (unsigned short)bfr(o[2]); ob.w = (unsigned short)bfr(o[3]);
    ((ushort4*)yb)[i4] = ob;
}

// ---------------- bn apply (single), inline stats, dual write ----------------
__global__ __launch_bounds__(256) void k_bn_apply_i(const float* __restrict__ x,
                                                    const float* __restrict__ sa,
                                                    const float* __restrict__ g,
                                                    const float* __restrict__ b,
                                                    float* __restrict__ y,
                                                    unsigned short* __restrict__ yb) {
    size_t i4 = (size_t)blockIdx.x * blockDim.x + threadIdx.x;
    int c = (int)((i4 & 63) << 2);
    float a[4], o[4];
    *(float4*)a = ((const float4*)x)[i4];
#pragma unroll
    for (int q = 0; q < 4; ++q) {
        int cc = c + q;
        float m = sa[cc] * INV_N;
        float r = rsqrtf(sa[256 + cc] * INV_N - m * m + 1e-5f);
        o[q] = (a[q] - m) * r * g[cc] + b[cc];
    }
    ((float4*)y)[i4] = *(float4*)o;
    ushort4 ob;
    ob.x = (unsigned short)bfr(o[0]); ob.y = (unsigned short)bfr(o[1]);
    ob.z = (unsigned short)bfr(o[2]); ob.w = (unsigned short)bfr(o[3]);
    ((ushort4*)yb)[i4] = ob;
}

// ---------------- MFMA flash attention: 128 q-rows x half-KV per block ----------------
// grid (128 bh, 4 i0, 2 z). Writes UNNORMALIZED partial O (f32) + per-row (m,l).
__global__ __launch_bounds__(256) void k_flash_mfma(const unsigned short* __restrict__ qkv,
                                                    float* __restrict__ opart,
                                                    float* __restrict__ ml) {
    __shared__ unsigned short Ks[64][72];
    __shared__ unsigned short VT[64][72];
    __shared__ unsigned short Ps[4][2][16][72];
    const int bh = blockIdx.x;
    const int b = bh >> 2, hh = bh & 3;
    const int i0 = blockIdx.y << 7;              // 128 q rows
    const int z = blockIdx.z;                    // KV half
    const int tid = threadIdx.x;
    const int w = tid >> 6, l = tid & 63;
    const int lr = l & 15, lq = l >> 4;
    const int hd = hh * DHD;
    const size_t rowbase = (size_t)(b * S_PG) * D3;

    s8v aq[2][2];
#pragma unroll
    for (int g = 0; g < 2; ++g) {
        const unsigned short* qrow = &qkv[rowbase + (size_t)(i0 + g * 64 + w * 16 + lr) * D3 + hd + lq * 8];
        aq[g][0] = *(const s8v*)&qrow[0];
        aq[g][1] = *(const s8v*)&qrow[32];
    }

    float mrow[2][4], lrow[2][4];
    f4v oacc[2][4] = {};
#pragma unroll
    for (int g = 0; g < 2; ++g)
#pragma unroll
        for (int j = 0; j < 4; ++j) { mrow[g][j] = -INFINITY; lrow[g][j] = 0.f; }

    const int skv = tid >> 2;                  // K staging: kv row 0..63
    const int sd0 = (tid & 3) << 4;            // K staging: d segment
    const int d0v = (tid >> 4) << 2;           // V staging: d block
    const int kv0 = (tid & 15) << 2;           // V staging: kv block

    const int jbeg = z * (S_PG / 2), jend = jbeg + S_PG / 2;
    for (int j0 = jbeg; j0 < jend; j0 += 64) {
        __syncthreads();
        {
            const unsigned short* kr = &qkv[rowbase + (size_t)(j0 + skv) * D3 + D + hd + sd0];
            *(uint4*)&Ks[skv][sd0]     = *(const uint4*)&kr[0];
            *(uint4*)&Ks[skv][sd0 + 8] = *(const uint4*)&kr[8];
            unsigned short vv[4][4];
#pragma unroll
            for (int i = 0; i < 4; ++i) {
                uint2 lv = *(const uint2*)&qkv[rowbase + (size_t)(j0 + kv0 + i) * D3 + D2 + hd + d0v];
                vv[i][0] = (unsigned short)(lv.x & 0xffffu);
                vv[i][1] = (unsigned short)(lv.x >> 16);
                vv[i][2] = (unsigned short)(lv.y & 0xffffu);
                vv[i][3] = (unsigned short)(lv.y >> 16);
            }
#pragma unroll
            for (int i2 = 0; i2 < 4; ++i2) {
                ushort4 o4;
                o4.x = vv[0][i2]; o4.y = vv[1][i2]; o4.z = vv[2][i2]; o4.w = vv[3][i2];
                *(ushort4*)&VT[d0v + i2][kv0] = o4;
            }
        }
        __syncthreads();
#pragma unroll
        for (int g = 0; g < 2; ++g) {
            f4v sc[4] = {};
#pragma unroll
            for (int nt = 0; nt < 4; ++nt) {
                s8v bk0 = *(const s8v*)&Ks[nt * 16 + lr][lq * 8];
                s8v bk1 = *(const s8v*)&Ks[nt * 16 + lr][32 + lq * 8];
                sc[nt] = __builtin_amdgcn_mfma_f32_16x16x32_bf16(aq[g][0], bk0, sc[nt], 0, 0, 0);
                sc[nt] = __builtin_amdgcn_mfma_f32_16x16x32_bf16(aq[g][1], bk1, sc[nt], 0, 0, 0);
            }
            float ps[4][4], alpha[4];
#pragma unroll
            for (int j = 0; j < 4; ++j) {
#pragma unroll
                for (int nt = 0; nt < 4; ++nt) ps[nt][j] = sc[nt][j];   // Q pre-scaled by 0.125*log2e
                float pm = fmaxf(fmaxf(ps[0][j], ps[1][j]), fmaxf(ps[2][j], ps[3][j]));
#pragma unroll
                for (int off = 1; off < 16; off <<= 1) pm = fmaxf(pm, __shfl_xor(pm, off));
                float mn = fmaxf(mrow[g][j], pm);
                alpha[j] = exp2f(mrow[g][j] - mn);
                float rs = 0.f;
#pragma unroll
                for (int nt = 0; nt < 4; ++nt) { ps[nt][j] = exp2f(ps[nt][j] - mn); rs += ps[nt][j]; }
#pragma unroll
                for (int off = 1; off < 16; off <<= 1) rs += __shfl_xor(rs, off);
                lrow[g][j] = lrow[g][j] * alpha[j] + rs;
                mrow[g][j] = mn;
            }
#pragma unroll
            for (int nt = 0; nt < 4; ++nt)
#pragma unroll
                for (int j = 0; j < 4; ++j)
                    Ps[w][g][lq * 4 + j][nt * 16 + lr] = (unsigned short)bfr(ps[nt][j]);
#pragma unroll
            for (int ntd = 0; ntd < 4; ++ntd)
#pragma unroll
                for (int j = 0; j < 4; ++j) oacc[g][ntd][j] *= alpha[j];
            s8v pa0 = *(const s8v*)&Ps[w][g][lr][lq * 8];
            s8v pa1 = *(const s8v*)&Ps[w][g][lr][32 + lq * 8];
#pragma unroll
            for (int ntd = 0; ntd < 4; ++ntd) {
                s8v bv0 = *(const s8v*)&VT[ntd * 16 + lr][lq * 8];
                s8v bv1 = *(const s8v*)&VT[ntd * 16 + lr][32 + lq * 8];
                oacc[g][ntd] = __builtin_amdgcn_mfma_f32_16x16x32_bf16(pa0, bv0, oacc[g][ntd], 0, 0, 0);
                oacc[g][ntd] = __builtin_amdgcn_mfma_f32_16x16x32_bf16(pa1, bv1, oacc[g][ntd], 0, 0, 0);
            }
        }
    }
    float* op = opart + (size_t)z * N_NODES * D;
#pragma unroll
    for (int g = 0; g < 2; ++g)
#pragma unroll
        for (int j = 0; j < 4; ++j) {
            int rrow = i0 + g * 64 + w * 16 + lq * 4 + j;
            int node = b * S_PG + rrow;
#pragma unroll
            for (int ntd = 0; ntd < 4; ++ntd)
                op[(size_t)node * D + hd + ntd * 16 + lr] = oacc[g][ntd][j];
            if (lr == 0) {
                size_t mlidx = (((size_t)z * 128 + bh) * S_PG + rrow) * 2;
                ml[mlidx] = mrow[g][j];
                ml[mlidx + 1] = lrow[g][j];
            }
        }
}

// ---------------- flash combine: merge the two KV halves exactly ----------------
__global__ __launch_bounds__(256) void k_flash_comb(const float* __restrict__ opart,
                                                    const float* __restrict__ ml,
                                                    unsigned short* __restrict__ ao) {
    size_t i4 = (size_t)blockIdx.x * 256 + threadIdx.x;   // one float4 of (node, d)
    int node = (int)(i4 >> 6);
    int dpos = (int)(i4 & 63) << 2;
    int head = dpos >> 6;
    int b = node >> 9, rrow = node & 511;
    int bh = (b << 2) | head;
    size_t m1i = (((size_t)0 * 128 + bh) * S_PG + rrow) * 2;
    size_t m2i = (((size_t)1 * 128 + bh) * S_PG + rrow) * 2;
    float m1 = ml[m1i], l1 = ml[m1i + 1];
    float m2 = ml[m2i], l2 = ml[m2i + 1];
    float mm = fmaxf(m1, m2);
    float w1 = exp2f(m1 - mm), w2 = exp2f(m2 - mm);
    float inv = 1.f / (l1 * w1 + l2 * w2);
    float s1 = w1 * inv, s2 = w2 * inv;
    float4 o1 = *(const float4*)&opart[(size_t)node * D + dpos];
    float4 o2 = *(const float4*)&opart[(size_t)N_NODES * D + (size_t)node * D + dpos];
    ushort4 o;
    o.x = (unsigned short)bfr(o1.x * s1 + o2.x * s2);
    o.y = (unsigned short)bfr(o1.y * s1 + o2.y * s2);
    o.z = (unsigned short)bfr(o1.z * s1 + o2.z * s2);
    o.w = (unsigned short)bfr(o1.w * s1 + o2.w * s2);
    *(ushort4*)&ao[(size_t)node * D + dpos] = o;
}

// ---------------- mean pool per graph (parallel: 32x8 blocks) ----------------
__global__ __launch_bounds__(256) void k_pool2(const float* __restrict__ h, float* __restrict__ g) {
    __shared__ float red[8][33];
    int b = blockIdx.x, cc = blockIdx.y;             // column chunk of 32
    int col = threadIdx.x & 31, rg = threadIdx.x >> 5;  // 8 row groups of 64
    const float* p = h + ((size_t)(b * S_PG + rg * 64)) * D + cc * 32 + col;
    float s = 0.f;
    for (int r = 0; r < 64; ++r) s += p[(size_t)r * D];
    red[rg][col] = s;
    __syncthreads();
    if (rg == 0) {
        float t = 0.f;
#pragma unroll
        for (int i = 0; i < 8; ++i) t += red[i][col];
        g[b * D + cc * 32 + col] = t * (1.f / (float)S_PG);
    }
}

// ---------------- final head, stage A: z chunk + sumsq partial (grid 32x3) ----------------
__global__ __launch_bounds__(256) void k_final_a(const float* __restrict__ g,
                                                 const float* __restrict__ pw1,
                                                 const float* __restrict__ pb1,
                                                 const float* __restrict__ pw2,
                                                 const float* __restrict__ pb2,
                                                 float* __restrict__ z,
                                                 float* __restrict__ zpart) {
    __shared__ float gs[D];
    __shared__ float ts[D];
    __shared__ float red[4];
    int b = blockIdx.x, ch = blockIdx.y, tid = threadIdx.x;
    gs[tid] = g[b * D + tid];
    __syncthreads();
    float acc = pb1[tid];
    for (int d = 0; d < D; ++d) acc = fmaf(gs[d], pw1[d * D + tid], acc);
    ts[tid] = fmaxf(acc, 0.f);
    __syncthreads();
    int j = ch * 256 + tid;
    float a = pb2[j];
    for (int d = 0; d < D; ++d) a = fmaf(ts[d], pw2[(size_t)d * OUTD + j], a);
    z[b * OUTD + j] = a;
    float ss = a * a;
#pragma unroll
    for (int o = 32; o >= 1; o >>= 1) ss += __shfl_xor(ss, o);
    if ((tid & 63) == 0) red[tid >> 6] = ss;
    __syncthreads();
    if (tid == 0) zpart[b * 3 + ch] = red[0] + red[1] + red[2] + red[3];
}

// ---------------- final head, stage B: normalize (grid 32x3) ----------------
__global__ __launch_bounds__(256) void k_final_b(const float* __restrict__ z,
                                                 const float* __restrict__ zpart,
                                                 float* __restrict__ out) {
    int b = blockIdx.x, ch = blockIdx.y, tid = threadIdx.x;
    float rn = rsqrtf(zpart[b * 3] + zpart[b * 3 + 1] + zpart[b * 3 + 2]);
    int j = ch * 256 + tid;
    out[b * OUTD + j] = z[b * OUTD + j] * rn;
}

extern "C" void kernel_launch(void* const* d_in, const int* in_sizes, int n_in,
                              void* d_out, int out_size, void* d_ws, size_t ws_size,
                              hipStream_t stream) {
    const int* x        = (const int*)d_in[0];
    const int* ea       = (const int*)d_in[1];
    const int* eidx     = (const int*)d_in[2];
    const float* atom_tab = (const float*)d_in[4];
    const float* bond_tab = (const float*)d_in[5];
    const float* elin_w = (const float*)d_in[6];
    const float* elin_b = (const float*)d_in[7];
    const float* eps    = (const float*)d_in[8];
    const float* gw1    = (const float*)d_in[9];
    const float* gb1    = (const float*)d_in[10];
    const float* gw2    = (const float*)d_in[11];
    const float* gb2    = (const float*)d_in[12];
    const float* aw_in  = (const float*)d_in[13];
    const float* ab_in  = (const float*)d_in[14];
    const float* aw_out = (const float*)d_in[15];
    const float* ab_out = (const float*)d_in[16];
    const float* n1g    = (const float*)d_in[17];
    const float* n1b    = (const float*)d_in[18];
    const float* n2g    = (const float*)d_in[19];
    const float* n2b    = (const float*)d_in[20];
    const float* n3g    = (const float*)d_in[21];
    const float* n3b    = (const float*)d_in[22];
    const float* mw1    = (const float*)d_in[23];
    const float* mb1    = (const float*)d_in[24];
    const float* mw2    = (const float*)d_in[25];
    const float* mb2    = (const float*)d_in[26];
    const float* pw1    = (const float*)d_in[27];
    const float* pb1    = (const float*)d_in[28];
    const float* pw2    = (const float*)d_in[29];
    const float* pb2    = (const float*)d_in[30];

    char* ws = (char*)d_ws;
    size_t off = 0;
    auto alloc = [&](size_t bytes) {
        void* p = ws + off;
        off += (bytes + 255) & ~(size_t)255;
        return p;
    };
    float*  h    = (float*)alloc((size_t)N_NODES * D * 4);
    float*  bufB = (float*)alloc((size_t)N_NODES * D * 4);
    float*  tmp1 = (float*)alloc((size_t)N_NODES * D * 4);
    unsigned short* hb = (unsigned short*)alloc((size_t)N_NODES * D * 2);
    char*   U    = (char*)alloc((size_t)N_NODES * D3 * 2);
    unsigned short* bfA = (unsigned short*)alloc((size_t)N_NODES * D3 * 2);
    unsigned short* WT  = (unsigned short*)alloc((size_t)NL * WT_PER_LAYER * 2);
    float*  bw   = (float*)alloc((size_t)NL * 66 * D * 4);
    unsigned short* ctb = (unsigned short*)alloc((size_t)NL * NCOMBO * D * 2);
    int*    deg  = (int*)alloc((size_t)N_NODES * 4);
    int*    row_ptr = (int*)alloc((size_t)(N_NODES + 1) * 4);
    int*    cursor  = (int*)alloc((size_t)N_NODES * 4);
    int2*   sorted  = (int2*)alloc((size_t)NE * 8);
    float*  statacc = (float*)alloc((size_t)12 * 512 * 4);   // 12 per-layer slots [sum|sum2]
    float*  opart = (float*)alloc((size_t)2 * N_NODES * D * 4);   // 32 MiB flash partials
    float*  ml    = (float*)alloc((size_t)2 * 128 * S_PG * 2 * 4);
    float*  g    = (float*)alloc((size_t)NB * D * 4);
    float*  z    = (float*)alloc((size_t)NB * OUTD * 4);
    float*  zpart = (float*)alloc((size_t)NB * 3 * 4);
    (void)ws_size; (void)in_sizes; (void)n_in; (void)out_size;

    float* tmp23 = (float*)U;
    unsigned short* qkv = (unsigned short*)U;
    unsigned short* aggb  = bfA;
    unsigned short* ao    = bfA;
    unsigned short* bufBb = bfA;
    unsigned short* hid   = bfA + (size_t)N_NODES * D;

    const int* srcp = eidx;
    const int* dstp = eidx + NE;
    const int EW = N_NODES * D / 1024;

    k_zero16k<<<N_NODES / 256, 256, 0, stream>>>(deg);
    k_zero_stats12<<<1, 256, 0, stream>>>(statacc);
    k_hist<<<NE / 256, 256, 0, stream>>>(dstp, deg);
    k_scan<<<1, 256, 0, stream>>>(deg, row_ptr, cursor);
    k_scatter<<<NE / 256, 256, 0, stream>>>(srcp, dstp, ea, cursor, sorted);
    k_atom_enc<<<N_NODES / 4, 256, 0, stream>>>(x, atom_tab, h, hb);
    k_bondw<<<NL * 66, 256, 0, stream>>>(bond_tab, elin_w, bw);
    k_combo<<<NL * NCOMBO, 256, 0, stream>>>(bw, elin_b, ctb);
    k_wcvt<<<NL * 768, 256, 0, stream>>>(gw1, gw2, aw_in, aw_out, mw1, mw2, WT);

    for (int l = 0; l < NL; ++l) {
        const unsigned short* WTl = WT + (size_t)l * WT_PER_LAYER;
        float* sl0 = statacc + (size_t)(l * 3 + 0) * 512;
        float* sl1 = statacc + (size_t)(l * 3 + 1) * 512;
        float* sl2 = statacc + (size_t)(l * 3 + 2) * 512;
        // --- GINE aggregation ---
        k_gine_agg<<<N_NODES / 4, 256, 0, stream>>>(hb, h, ctb + (size_t)l * NCOMBO * D, eps, l,
                                                    row_ptr, sorted, aggb);
        // --- merged gw1 (relu, ->hid) + aw_in (->qkv, Q prescaled) ---
        k_mm2_dual<<<dim3(10, N_NODES / 128), 256, 0, stream>>>(
            aggb, WTl + 0, gb1 + (size_t)l * D2, hid, D2, 4,
            hb, WTl + 262144, ab_in + (size_t)l * D3, qkv, D3, D);
        // --- flash attention: KV-split x2, then exact combine ---
        k_flash_mfma<<<dim3(NB * NH, S_PG / 128, 2), 256, 0, stream>>>(qkv, opart, ml);
        k_flash_comb<<<N_NODES * D / 1024, 256, 0, stream>>>(opart, ml, ao);
        // --- merged gw2 (K=512, ->tmp1, stats sl0) + aw_out (K=256, ->tmp23, stats sl1) ---
        k_mm64_dual<<<dim3(4, N_NODES / 64), 256, 0, stream>>>(
            hid, WTl + 131072, gb2 + (size_t)l * D, h, tmp1, sl0, D2, 2,
            ao, WTl + 458752, ab_out + (size_t)l * D, h, tmp23, sl1, D);
        // --- combine bn1+bn2 (inline stats) ---
        k_bn12i<<<EW, 256, 0, stream>>>(tmp1, sl0, n1g + l * D, n1b + l * D,
                                        tmp23, sl1, n2g + l * D, n2b + l * D, bufB, bufBb);
        // --- MLP ---
        k_mm2<1, 0, 1, 0><<<dim3(D2 / 128, N_NODES / 128), 256, 0, stream>>>(
            bufBb, WTl + 524288, mb1 + (size_t)l * D2, nullptr, hid, nullptr, N_NODES, D2, D);
        k_mm64<0, 1, 0, 1><<<dim3(D / 128, N_NODES / 64), 256, 0, stream>>>(
            hid, WTl + 655360, mb2 + (size_t)l * D, bufB, tmp23, sl2, N_NODES, D, D2);
        k_bn_apply_i<<<EW, 256, 0, stream>>>(tmp23, sl2, n3g + l * D, n3b + l * D, h, hb);
    }
    k_pool2<<<dim3(NB, 8), 256, 0, stream>>>(h, g);
    k_final_a<<<dim3(NB, 3), 256, 0, stream>>>(g, pw1, pb1, pw2, pb2, z, zpart);
    k_final_b<<<dim3(NB, 3), 256, 0, stream>>>(z, zpart, (float*)d_out);
}